// Round 1
// baseline (29187.299 us; speedup 1.0000x reference)
//
#include <hip/hip_runtime.h>
#include <hip/hip_cooperative_groups.h>
#include <math.h>

namespace cg = cooperative_groups;

#define B_   64
#define H_   300
#define V_   32000
#define T_   48
#define NBLK 250
#define NTHR 256
#define VT   128     // v-columns per block tile
#define KC   60      // k per LDS chunk
#define NK4  15      // float4 groups per row chunk
#define NCH  5       // K chunks (5*60 = 300)
#define NJB  150     // blocks participating in GRU
#define JPB  2       // h-columns (j) per GRU block

struct Ws {
  unsigned long long amax[T_ * B_]; // packed (ord(maxval)<<32)|(~idx)
  float sum[T_ * B_];               // sum of exp(logit) per (t,b)
  float h[2][B_ * H_];              // ping-pong hidden state
};

__device__ __forceinline__ unsigned f2ord(float f) {
  unsigned u = __float_as_uint(f);
  return (u & 0x80000000u) ? ~u : (u | 0x80000000u);
}

// GRU cell for j-columns [j0, j0+JPB) of all 64 rows.
// Thread layout: b = tid&63, q = tid>>6 covers k4 groups [q*19, q*19+19) (masked at 75).
__device__ void gru_phase(int tid, int j0, int tok,
    const float* __restrict__ embed, const float* __restrict__ w_ih,
    const float* __restrict__ w_hh, const float* __restrict__ b_ih,
    const float* __restrict__ b_hh, const float* __restrict__ hsrc,
    float* __restrict__ hdst, float* lds)
{
  const int b = tid & 63;
  const int q = tid >> 6;
  const float* xr = embed + (size_t)tok * H_;
  const float* hr = hsrc + (size_t)b * H_;

  float4 xv[19], hv[19];
#pragma unroll
  for (int n = 0; n < 19; ++n) {
    int k4 = q * 19 + n;
    bool ok = (k4 < 75);
    int k = k4 * 4;
    xv[n] = ok ? *(const float4*)(xr + k) : make_float4(0.f, 0.f, 0.f, 0.f);
    hv[n] = ok ? *(const float4*)(hr + k) : make_float4(0.f, 0.f, 0.f, 0.f);
  }

#pragma unroll
  for (int jl = 0; jl < JPB; ++jl) {
    int j = j0 + jl;
    float ar = 0.f, az = 0.f, an = 0.f, br = 0.f, bz = 0.f, bn = 0.f;
#pragma unroll
    for (int n = 0; n < 19; ++n) {
      int k4 = q * 19 + n;
      bool ok = (k4 < 75);
      int k = k4 * 4;
      float4 z4 = make_float4(0.f, 0.f, 0.f, 0.f);
      float4 wr = ok ? *(const float4*)(w_ih + (size_t)j * H_ + k) : z4;
      float4 wz = ok ? *(const float4*)(w_ih + (size_t)(300 + j) * H_ + k) : z4;
      float4 wn = ok ? *(const float4*)(w_ih + (size_t)(600 + j) * H_ + k) : z4;
      float4 ur = ok ? *(const float4*)(w_hh + (size_t)j * H_ + k) : z4;
      float4 uz = ok ? *(const float4*)(w_hh + (size_t)(300 + j) * H_ + k) : z4;
      float4 un = ok ? *(const float4*)(w_hh + (size_t)(600 + j) * H_ + k) : z4;
      ar = fmaf(wr.x, xv[n].x, ar); ar = fmaf(wr.y, xv[n].y, ar);
      ar = fmaf(wr.z, xv[n].z, ar); ar = fmaf(wr.w, xv[n].w, ar);
      az = fmaf(wz.x, xv[n].x, az); az = fmaf(wz.y, xv[n].y, az);
      az = fmaf(wz.z, xv[n].z, az); az = fmaf(wz.w, xv[n].w, az);
      an = fmaf(wn.x, xv[n].x, an); an = fmaf(wn.y, xv[n].y, an);
      an = fmaf(wn.z, xv[n].z, an); an = fmaf(wn.w, xv[n].w, an);
      br = fmaf(ur.x, hv[n].x, br); br = fmaf(ur.y, hv[n].y, br);
      br = fmaf(ur.z, hv[n].z, br); br = fmaf(ur.w, hv[n].w, br);
      bz = fmaf(uz.x, hv[n].x, bz); bz = fmaf(uz.y, hv[n].y, bz);
      bz = fmaf(uz.z, hv[n].z, bz); bz = fmaf(uz.w, hv[n].w, bz);
      bn = fmaf(un.x, hv[n].x, bn); bn = fmaf(un.y, hv[n].y, bn);
      bn = fmaf(un.z, hv[n].z, bn); bn = fmaf(un.w, hv[n].w, bn);
    }
    float* p = lds + ((q * 64 + b) * JPB + jl) * 6;
    p[0] = ar; p[1] = az; p[2] = an; p[3] = br; p[4] = bz; p[5] = bn;
  }
  __syncthreads();
  for (int item = tid; item < B_ * JPB; item += NTHR) {
    int bb = item & 63, jl = item >> 6;
    int j = j0 + jl;
    float gr = b_ih[j], gz = b_ih[300 + j], gn = b_ih[600 + j];
    float pr = b_hh[j], pz = b_hh[300 + j], pn = b_hh[600 + j];
#pragma unroll
    for (int q2 = 0; q2 < 4; ++q2) {
      const float* p = lds + ((q2 * 64 + bb) * JPB + jl) * 6;
      gr += p[0]; gz += p[1]; gn += p[2]; pr += p[3]; pz += p[4]; pn += p[5];
    }
    float r = 1.f / (1.f + expf(-(gr + pr)));
    float z = 1.f / (1.f + expf(-(gz + pz)));
    float n = tanhf(gn + r * pn);
    hdst[(size_t)bb * H_ + j] = (1.f - z) * n + z * hsrc[(size_t)bb * H_ + j];
  }
}

extern "C" __global__ void __launch_bounds__(NTHR, 2)
decoder_kernel(const int* __restrict__ tok_in, const float* __restrict__ h0,
               const float* __restrict__ embed, const float* __restrict__ w_ih,
               const float* __restrict__ w_hh, const float* __restrict__ b_ih,
               const float* __restrict__ b_hh, const float* __restrict__ w_out,
               const float* __restrict__ b_out, float* __restrict__ out, Ws* ws)
{
  __shared__ __align__(16) float lds[11520]; // 46.08 KB: W tile + h tile; reused for merge/GRU
  float4* lds4 = (float4*)lds;
  cg::grid_group grid = cg::this_grid();
  const int tid = threadIdx.x;
  const int blk = blockIdx.x;

  // init workspace (d_ws is poisoned 0xAA every launch)
  for (int i = blk * NTHR + tid; i < T_ * B_; i += NBLK * NTHR) {
    ws->amax[i] = 0ull;
    ws->sum[i] = 0.f;
  }
  __threadfence();
  grid.sync();

  // prologue: h1 = GRU(h0, embed[input_tokens]) -> ws->h[1]
  if (blk < NJB) {
    int tok = tok_in[tid & 63];
    gru_phase(tid, blk * JPB, tok, embed, w_ih, w_hh, b_ih, b_hh, h0, ws->h[1], lds);
  }
  __threadfence();
  grid.sync();

  const int kh = tid >> 7;        // k-half: 0 -> k4 0..7, 1 -> k4 8..14
  const int txy = tid & 127;
  const int tx = txy & 15;        // v sub-tile (8 v each)
  const int ty = txy >> 4;        // b sub-tile (8 b each)
  const int v0 = blk * VT;

  for (int t = 0; t < T_; ++t) {
    __threadfence(); // acquire: h ping-pong buffers are re-read across iterations
    const float* hcur = ws->h[(t + 1) & 1];

    float acc[8][8]; // [j(b)][i(v)]
#pragma unroll
    for (int j = 0; j < 8; ++j)
#pragma unroll
      for (int i = 0; i < 8; ++i) acc[j][i] = 0.f;

    for (int ch = 0; ch < NCH; ++ch) {
      const int kb = ch * KC;
      __syncthreads();
      // stage W tile [VT][KC], XOR-swizzled on v
      for (int idx = tid; idx < VT * NK4; idx += NTHR) {
        int v = idx / NK4, k4 = idx % NK4;
        const float4 w = *(const float4*)(w_out + (size_t)(v0 + v) * H_ + kb + k4 * 4);
        int sv = (v & ~7) | ((v ^ (v >> 3)) & 7);
        lds4[k4 * VT + sv] = w;
      }
      // stage h tile [64][KC], XOR-swizzled on b
      for (int idx = tid; idx < 64 * NK4; idx += NTHR) {
        int b = idx / NK4, k4 = idx % NK4;
        const float4 hvv = *(const float4*)(hcur + (size_t)b * H_ + kb + k4 * 4);
        int sb = (b & ~7) | ((b ^ (b >> 3)) & 7);
        lds4[1920 + k4 * 64 + sb] = hvv;
      }
      __syncthreads();
      const int k4lo = kh ? 8 : 0;
      const int k4n  = kh ? 7 : 8;
      for (int k4i = 0; k4i < k4n; ++k4i) {
        const int k4 = k4lo + k4i;
        float4 wf[8], hf[8];
#pragma unroll
        for (int i = 0; i < 8; ++i) wf[i] = lds4[k4 * VT + tx * 8 + (i ^ (tx & 7))];
#pragma unroll
        for (int j = 0; j < 8; ++j) hf[j] = lds4[1920 + k4 * 64 + ty * 8 + (j ^ (ty & 7))];
#pragma unroll
        for (int j = 0; j < 8; ++j)
#pragma unroll
          for (int i = 0; i < 8; ++i) {
            acc[j][i] = fmaf(wf[i].x, hf[j].x, acc[j][i]);
            acc[j][i] = fmaf(wf[i].y, hf[j].y, acc[j][i]);
            acc[j][i] = fmaf(wf[i].z, hf[j].z, acc[j][i]);
            acc[j][i] = fmaf(wf[i].w, hf[j].w, acc[j][i]);
          }
      }
    }
    __syncthreads();
    // merge k-halves through LDS (swizzled)
    if (kh == 1) {
#pragma unroll
      for (int j = 0; j < 8; ++j) {
        lds4[txy * 16 + ((j * 2)     ^ (txy & 7))] = make_float4(acc[j][0], acc[j][1], acc[j][2], acc[j][3]);
        lds4[txy * 16 + ((j * 2 + 1) ^ (txy & 7))] = make_float4(acc[j][4], acc[j][5], acc[j][6], acc[j][7]);
      }
    }
    __syncthreads();
    if (kh == 0) {
      const float4 bo0 = *(const float4*)(b_out + v0 + tx * 8);
      const float4 bo1 = *(const float4*)(b_out + v0 + tx * 8 + 4);
#pragma unroll
      for (int j = 0; j < 8; ++j) {
        float4 u0 = lds4[txy * 16 + ((j * 2)     ^ (txy & 7))];
        float4 u1 = lds4[txy * 16 + ((j * 2 + 1) ^ (txy & 7))];
        acc[j][0] += u0.x + bo0.x; acc[j][1] += u0.y + bo0.y;
        acc[j][2] += u0.z + bo0.z; acc[j][3] += u0.w + bo0.w;
        acc[j][4] += u1.x + bo1.x; acc[j][5] += u1.y + bo1.y;
        acc[j][6] += u1.z + bo1.z; acc[j][7] += u1.w + bo1.w;
      }
      // per-row partials: direct sum(exp) (|logit| <= ~15, fp32-safe) + packed argmax
#pragma unroll
      for (int j = 0; j < 8; ++j) {
        int b = ty * 8 + j;
        float m = acc[j][0]; int mi = v0 + tx * 8;
#pragma unroll
        for (int i = 1; i < 8; ++i)
          if (acc[j][i] > m) { m = acc[j][i]; mi = v0 + tx * 8 + i; }
        float s = 0.f;
#pragma unroll
        for (int i = 0; i < 8; ++i) s += expf(acc[j][i]);
        for (int off = 1; off < 16; off <<= 1) {
          float om = __shfl_xor(m, off);
          int   omi = __shfl_xor(mi, off);
          float os = __shfl_xor(s, off);
          s += os;
          if (om > m || (om == m && omi < mi)) { m = om; mi = omi; }
        }
        if (tx == 0) {
          atomicAdd(&ws->sum[t * B_ + b], s);
          unsigned long long key =
              ((unsigned long long)f2ord(m) << 32) | (unsigned)(0xFFFFFFFFu - (unsigned)mi);
          atomicMax(&ws->amax[t * B_ + b], key);
        }
      }
    }
    __threadfence();
    grid.sync();
    __threadfence();

    // phase 2: logp writes (acc is still live in registers)
    if (kh == 0) {
#pragma unroll
      for (int j = 0; j < 8; ++j) {
        int b = ty * 8 + j;
        float lse = logf(ws->sum[t * B_ + b]);
        float* o = out + (size_t)b * ((size_t)T_ * V_) + (size_t)t * V_ + v0 + tx * 8;
        ((float4*)o)[0] = make_float4(acc[j][0] - lse, acc[j][1] - lse, acc[j][2] - lse, acc[j][3] - lse);
        ((float4*)o)[1] = make_float4(acc[j][4] - lse, acc[j][5] - lse, acc[j][6] - lse, acc[j][7] - lse);
      }
    }
    // ids output (block 0, idle kh==1 threads)
    if (blk == 0 && tid >= 128 && tid < 192) {
      int b = tid - 128;
      unsigned idx = 0xFFFFFFFFu - (unsigned)(ws->amax[t * B_ + b] & 0xFFFFFFFFull);
      out[(size_t)B_ * T_ * V_ + (size_t)b * T_ + t] = (float)idx;
    }
    // GRU for next step: h_{t+2} = GRU(h_{t+1}, embed[pred_t])
    if (t < T_ - 1 && blk < NJB) {
      __syncthreads();
      unsigned long long a = ws->amax[t * B_ + (tid & 63)];
      int tok = (int)(0xFFFFFFFFu - (unsigned)(a & 0xFFFFFFFFull));
      gru_phase(tid, blk * JPB, tok, embed, w_ih, w_hh, b_ih, b_hh,
                ws->h[(t + 1) & 1], ws->h[t & 1], lds);
    }
    __threadfence();
    grid.sync();
  }
}

extern "C" void kernel_launch(void* const* d_in, const int* in_sizes, int n_in,
                              void* d_out, int out_size, void* d_ws, size_t ws_size,
                              hipStream_t stream)
{
  const int*   tok  = (const int*)  d_in[0];
  const float* h0   = (const float*)d_in[1];
  // d_in[2] = max_len (T=48, compile-time)
  const float* emb  = (const float*)d_in[3];
  const float* wih  = (const float*)d_in[4];
  const float* whh  = (const float*)d_in[5];
  const float* bih  = (const float*)d_in[6];
  const float* bhh  = (const float*)d_in[7];
  const float* wout = (const float*)d_in[8];
  const float* bout = (const float*)d_in[9];
  float* out = (float*)d_out;
  Ws* ws = (Ws*)d_ws;

  void* args[] = {(void*)&tok, (void*)&h0, (void*)&emb, (void*)&wih, (void*)&whh,
                  (void*)&bih, (void*)&bhh, (void*)&wout, (void*)&bout,
                  (void*)&out, (void*)&ws};
  hipLaunchCooperativeKernel((const void*)decoder_kernel, dim3(NBLK), dim3(NTHR),
                             args, 0, stream);
}

// Round 5
// 9941.929 us; speedup vs baseline: 2.9358x; 2.9358x over previous
//
#include <hip/hip_runtime.h>
#include <hip/hip_cooperative_groups.h>
#include <math.h>

namespace cg = cooperative_groups;

#define B_   64
#define H_   300
#define V_   32000
#define T_   48
#define NBLK 250
#define NTHR 256
#define VT   128     // v-columns per block tile
#define NCH  5       // K chunks of 60 (15 float4) each
#define NJB  150     // blocks doing GRU (2 j-columns each)
#define HOFF 1920    // float4 offset of h tile in LDS

// R1's validated swizzle: v -> (v&~7) | ((v ^ (v>>3)) & 7)
#define SWZ8(v) (((v) & ~7) | (((v) ^ ((v) >> 3)) & 7))

struct Ws {
  unsigned long long amax[T_ * B_]; // packed (ord(maxval)<<32)|(~idx)
  float sum[T_ * B_];               // sum of exp(logit) per (t,b)
  float h[2][B_ * H_];              // ping-pong hidden state
};

__device__ __forceinline__ unsigned f2ord(float f) {
  unsigned u = __float_as_uint(f);
  return (u & 0x80000000u) ? ~u : (u | 0x80000000u);
}

// GRU cell for j-columns {j0, j0+1}. Single pass over k: load x4/h4 once,
// accumulate all 12 gate partials (no big register caches -> no spill).
// Per-accumulator FMA chain order is IDENTICAL to the R1 kernel (k4 asc, xyzw).
__device__ __forceinline__ void gru_phase(int tid, int j0, int tok,
    const float* __restrict__ embed,
    const float* __restrict__ w_ih, const float* __restrict__ w_hh,
    const float* __restrict__ b_ih, const float* __restrict__ b_hh,
    const float* __restrict__ hsrc, float* __restrict__ hdst, float* pf)
{
  const int b = tid & 63, q = tid >> 6;
  const float* xr = embed + (size_t)tok * H_;
  const float* hr = hsrc + (size_t)b * H_;

  float ga[2][3] = {{0.f,0.f,0.f},{0.f,0.f,0.f}};  // x @ w_ih.T partials (r,z,n)
  float gc[2][3] = {{0.f,0.f,0.f},{0.f,0.f,0.f}};  // h @ w_hh.T partials
  for (int n = 0; n < 19; ++n) {
    int k4 = q * 19 + n;
    if (k4 < 75) {
      float4 x4 = *(const float4*)(xr + k4 * 4);
      float4 h4 = *(const float4*)(hr + k4 * 4);
#pragma unroll
      for (int jl = 0; jl < 2; ++jl) {
#pragma unroll
        for (int g = 0; g < 3; ++g) {
          float4 w = *(const float4*)(w_ih + (size_t)(g * H_ + j0 + jl) * H_ + k4 * 4);
          float a = ga[jl][g];
          a = fmaf(w.x, x4.x, a); a = fmaf(w.y, x4.y, a);
          a = fmaf(w.z, x4.z, a); a = fmaf(w.w, x4.w, a);
          ga[jl][g] = a;
          float4 u = *(const float4*)(w_hh + (size_t)(g * H_ + j0 + jl) * H_ + k4 * 4);
          float c = gc[jl][g];
          c = fmaf(u.x, h4.x, c); c = fmaf(u.y, h4.y, c);
          c = fmaf(u.z, h4.z, c); c = fmaf(u.w, h4.w, c);
          gc[jl][g] = c;
        }
      }
    }
  }
#pragma unroll
  for (int jl = 0; jl < 2; ++jl) {
    int base = (q * 64 + b) * 13 + jl * 6; // stride 13: gcd(13,32)=1, conflict-free
    pf[base + 0] = ga[jl][0]; pf[base + 1] = ga[jl][1]; pf[base + 2] = ga[jl][2];
    pf[base + 3] = gc[jl][0]; pf[base + 4] = gc[jl][1]; pf[base + 5] = gc[jl][2];
  }
  __syncthreads();
  if (tid < 128) {
    int bb = tid & 63, jl = tid >> 6;
    int j = j0 + jl;
    float gr = b_ih[j], gz = b_ih[H_ + j], gn = b_ih[2 * H_ + j];
    float pr = b_hh[j], pz = b_hh[H_ + j], pn = b_hh[2 * H_ + j];
#pragma unroll
    for (int q2 = 0; q2 < 4; ++q2) {
      const float* p = pf + (q2 * 64 + bb) * 13 + jl * 6;
      gr += p[0]; gz += p[1]; gn += p[2]; pr += p[3]; pz += p[4]; pn += p[5];
    }
    float r = 1.f / (1.f + expf(-(gr + pr)));
    float z = 1.f / (1.f + expf(-(gz + pz)));
    float n = tanhf(gn + r * pn);
    hdst[(size_t)bb * H_ + j] = (1.f - z) * n + z * hsrc[(size_t)bb * H_ + j];
  }
}

extern "C" __global__ void __launch_bounds__(NTHR, 2)
decoder_kernel(const int* __restrict__ tok_in, const float* __restrict__ h0,
               const float* __restrict__ embed, const float* __restrict__ w_ih,
               const float* __restrict__ w_hh, const float* __restrict__ b_ih,
               const float* __restrict__ b_hh, const float* __restrict__ w_out,
               const float* __restrict__ b_out, float* __restrict__ out, Ws* ws)
{
  __shared__ __align__(16) float4 lds4[2880]; // 46.08 KB: W tile + h tile (reused for GRU partials)
  float* pf = (float*)lds4;
  cg::grid_group grid = cg::this_grid();
  const int tid = threadIdx.x;
  const int blk = blockIdx.x;
  const int j0 = blk * 2;

  // init workspace (d_ws is poisoned 0xAA every launch)
  for (int i = blk * NTHR + tid; i < T_ * B_; i += NBLK * NTHR) {
    ws->amax[i] = 0ull;
    ws->sum[i] = 0.f;
  }
  __threadfence();
  grid.sync();

  // prologue: h1 = GRU(h0, embed[input_tokens]) -> ws->h[1]
  if (blk < NJB) {
    int tok = tok_in[tid & 63];
    gru_phase(tid, j0, tok, embed, w_ih, w_hh, b_ih, b_hh, h0, ws->h[1], pf);
  }
  __threadfence();
  grid.sync();

  const int tx = tid & 15;   // 8 v-columns each
  const int ty = tid >> 4;   // 4 b-rows each
  const int v0 = blk * VT;
  const float* wbase = w_out + (size_t)v0 * H_;
  const float4 bo0 = *(const float4*)(b_out + v0 + tx * 8);
  const float4 bo1 = *(const float4*)(b_out + v0 + tx * 8 + 4);

  for (int t = 0; t < T_; ++t) {
    const float* hcur = ws->h[(t + 1) & 1];
    // two accumulators replicate R1's kh-split summation order exactly
    float alo[4][8], ahi[4][8];
#pragma unroll
    for (int j = 0; j < 4; ++j)
#pragma unroll
      for (int i = 0; i < 8; ++i) { alo[j][i] = 0.f; ahi[j][i] = 0.f; }

    for (int ch = 0; ch < NCH; ++ch) {
      const int kb = ch * 60;
      __syncthreads();
      // stage W tile [15 k4][128 v], swizzled on v
#pragma unroll
      for (int it = 0; it < 8; ++it) {
        int idx = it * 256 + tid;
        int v = idx >> 4, k4 = idx & 15;
        if (k4 < 15)
          lds4[k4 * VT + SWZ8(v)] =
              *(const float4*)(wbase + (size_t)v * H_ + kb + k4 * 4);
      }
      // stage h tile [15 k4][64 b], swizzled on b
#pragma unroll
      for (int it = 0; it < 4; ++it) {
        int idx = it * 256 + tid;
        int b = idx >> 4, k4 = idx & 15;
        if (k4 < 15)
          lds4[HOFF + k4 * 64 + SWZ8(b)] =
              *(const float4*)(hcur + (size_t)b * H_ + kb + k4 * 4);
      }
      __syncthreads();
#pragma unroll
      for (int k4 = 0; k4 < 15; ++k4) {
        float4 wf[8], hf[4];
#pragma unroll
        for (int i = 0; i < 8; ++i) wf[i] = lds4[k4 * VT + SWZ8(tx * 8 + i)];
#pragma unroll
        for (int j = 0; j < 4; ++j) hf[j] = lds4[HOFF + k4 * 64 + SWZ8(ty * 4 + j)];
#define FMAS(A)                                                     \
        for (int j = 0; j < 4; ++j)                                 \
          for (int i = 0; i < 8; ++i) {                             \
            A[j][i] = fmaf(wf[i].x, hf[j].x, A[j][i]);              \
            A[j][i] = fmaf(wf[i].y, hf[j].y, A[j][i]);              \
            A[j][i] = fmaf(wf[i].z, hf[j].z, A[j][i]);              \
            A[j][i] = fmaf(wf[i].w, hf[j].w, A[j][i]);              \
          }
        if (k4 < 8) { FMAS(alo) } else { FMAS(ahi) }
#undef FMAS
      }
    }
    // merge halves + bias in R1's exact order: alo + (ahi + bias)
    float acc[4][8];
#pragma unroll
    for (int j = 0; j < 4; ++j) {
      acc[j][0] = alo[j][0] + (ahi[j][0] + bo0.x);
      acc[j][1] = alo[j][1] + (ahi[j][1] + bo0.y);
      acc[j][2] = alo[j][2] + (ahi[j][2] + bo0.z);
      acc[j][3] = alo[j][3] + (ahi[j][3] + bo0.w);
      acc[j][4] = alo[j][4] + (ahi[j][4] + bo1.x);
      acc[j][5] = alo[j][5] + (ahi[j][5] + bo1.y);
      acc[j][6] = alo[j][6] + (ahi[j][6] + bo1.z);
      acc[j][7] = alo[j][7] + (ahi[j][7] + bo1.w);
    }
    // per-row partials: max/argmax + sum(exp) (|logit| small, fp32-safe)
#pragma unroll
    for (int j = 0; j < 4; ++j) {
      int b = ty * 4 + j;
      float m = acc[j][0]; int mi = v0 + tx * 8;
#pragma unroll
      for (int i = 1; i < 8; ++i)
        if (acc[j][i] > m) { m = acc[j][i]; mi = v0 + tx * 8 + i; }
      float s = 0.f;
#pragma unroll
      for (int i = 0; i < 8; ++i) s += expf(acc[j][i]);
      for (int off = 1; off < 16; off <<= 1) {
        float om = __shfl_xor(m, off);
        int   omi = __shfl_xor(mi, off);
        float os = __shfl_xor(s, off);
        s += os;
        if (om > m || (om == m && omi < mi)) { m = om; mi = omi; }
      }
      if (tx == 0) {
        atomicAdd(&ws->sum[t * B_ + b], s);
        unsigned long long key =
            ((unsigned long long)f2ord(m) << 32) | (unsigned)(0xFFFFFFFFu - (unsigned)mi);
        atomicMax(&ws->amax[t * B_ + b], key);
      }
    }
    __threadfence();
    grid.sync();
    __threadfence();

    // phase 2: logp writes (acc live in registers)
#pragma unroll
    for (int j = 0; j < 4; ++j) {
      int b = ty * 4 + j;
      float lse = logf(ws->sum[t * B_ + b]);
      float* o = out + (size_t)b * ((size_t)T_ * V_) + (size_t)t * V_ + v0 + tx * 8;
      ((float4*)o)[0] = make_float4(acc[j][0] - lse, acc[j][1] - lse, acc[j][2] - lse, acc[j][3] - lse);
      ((float4*)o)[1] = make_float4(acc[j][4] - lse, acc[j][5] - lse, acc[j][6] - lse, acc[j][7] - lse);
    }
    // ids output
    if (blk == 0 && tid >= 128 && tid < 192) {
      int b = tid - 128;
      unsigned idx = 0xFFFFFFFFu - (unsigned)(ws->amax[t * B_ + b] & 0xFFFFFFFFull);
      out[(size_t)B_ * T_ * V_ + (size_t)b * T_ + t] = (float)idx;
    }
    // GRU for next step: h_{t+2} = GRU(h_{t+1}, embed[pred_t])
    if (t < T_ - 1 && blk < NJB) {
      unsigned long long a = ws->amax[t * B_ + (tid & 63)];
      int tok = (int)(0xFFFFFFFFu - (unsigned)(a & 0xFFFFFFFFull));
      gru_phase(tid, j0, tok, embed, w_ih, w_hh, b_ih, b_hh,
                ws->h[(t + 1) & 1], ws->h[t & 1], pf);
    }
    __threadfence();
    grid.sync();
  }
}

extern "C" void kernel_launch(void* const* d_in, const int* in_sizes, int n_in,
                              void* d_out, int out_size, void* d_ws, size_t ws_size,
                              hipStream_t stream)
{
  const int*   tok  = (const int*)  d_in[0];
  const float* h0   = (const float*)d_in[1];
  // d_in[2] = max_len (T=48, compile-time)
  const float* emb  = (const float*)d_in[3];
  const float* wih  = (const float*)d_in[4];
  const float* whh  = (const float*)d_in[5];
  const float* bih  = (const float*)d_in[6];
  const float* bhh  = (const float*)d_in[7];
  const float* wout = (const float*)d_in[8];
  const float* bout = (const float*)d_in[9];
  float* out = (float*)d_out;
  Ws* ws = (Ws*)d_ws;

  void* args[] = {(void*)&tok, (void*)&h0, (void*)&emb, (void*)&wih, (void*)&whh,
                  (void*)&bih, (void*)&bhh, (void*)&wout, (void*)&bout,
                  (void*)&out, (void*)&ws};
  hipLaunchCooperativeKernel((const void*)decoder_kernel, dim3(NBLK), dim3(NTHR),
                             args, 0, stream);
}